// Round 1
// baseline (189.278 us; speedup 1.0000x reference)
//
#include <hip/hip_runtime.h>
#include <math.h>

// Tropical (max-plus) matmul: out[b,o] = max_k ( x[b,k] + W[o,k] )
// x: (2048,512) f32, W: (512,512) f32, out: (2048,512) f32.
//
// R3 post-mortem: VALUBusy 26% ~= occupancy 19.6% -> latency-bound; grid
// (512 blocks) caps CU at 2 blocks = 2 waves/SIMD even though VGPR=112 and
// LDS=32KB allow 4. B-operand LDS reads are an inherent 4-way bank
// conflict (1.05M cycles).
// R4: (a) SPLITK=16 -> 1024 blocks -> 4 waves/SIMD (launch_bounds(256,4),
// LDS 128KB/CU); (b) 16B-chunk XOR swizzle inside each kp row so B reads
// are 2-way (free) instead of 4-way. SK8 path kept as ws_size fallback.

typedef float f2v __attribute__((ext_vector_type(2)));
typedef float f4v __attribute__((ext_vector_type(4)));

#define B_ROWS 2048
#define K_DIM  512
#define O_DIM  512
#define BM 128
#define BN 128
#define BK 32

// Swizzle 16B chunks (2 f2v) within a 1KB kp-row: c ^= bit3 -> spreads the
// stride-32B read pattern across all 8 bank-groups (4-way -> 2-way = free).
__device__ __forceinline__ int swz(int c) { return c ^ ((c >> 3) & 1); }

__device__ __forceinline__ void atomic_max_f32(float* p, float v) {
    unsigned int* up = (unsigned int*)p;
    unsigned int cur = *(volatile unsigned int*)up;
    while (__uint_as_float(cur) < v) {
        unsigned int assumed = cur;
        cur = atomicCAS(up, assumed, __float_as_uint(v));
        if (cur == assumed) break;
    }
}

template <int SPLITK, int MINWAVES, bool USE_WS>
__global__ __launch_bounds__(256, MINWAVES) void tropical_main(
    const float* __restrict__ x, const float* __restrict__ W,
    float* __restrict__ dst)  // USE_WS: ws partials base; else d_out
{
    constexpr int KRANGE = K_DIM / SPLITK;  // 32 (SK16) / 64 (SK8)
    constexpr int KT     = KRANGE / BK;     // 1 / 2

    // k-pair-major LDS: element [kp][r] = { v[2kp][r], v[2kp+1][r] },
    // with 16B chunks XOR-swizzled within each kp row (both sides).
    __shared__ __align__(16) f2v xs2[BK / 2][BM];   // 16 KB
    __shared__ __align__(16) f2v ws2[BK / 2][BN];   // 16 KB

    const int t  = threadIdx.x;
    const int bx = blockIdx.x;
    const int bn = (bx & 3) * BN;          // 4 N-tiles
    const int bm = ((bx >> 2) & 15) * BM;  // 16 M-tiles
    const int ks = bx >> 6;                // SPLITK K-splits
    const int k0 = ks * KRANGE;

    // Staging: thread t covers 16 consecutive k of one row (4x float4).
    const int sr  = t & 127;          // row within tile
    const int kh  = t >> 7;           // 0/1 -> k-offset 16*kh, kp-offset 8*kh
    const int srs = swz(sr >> 1) * 2 + (sr & 1);   // swizzled f2v slot

    // Compute: 16x16 thread grid, 8x8 register tile as (4+4)x(4+4).
    const int tx = t & 15;
    const int ty = t >> 4;
    const int c0 = tx * 4, c1 = 64 + tx * 4;
    const int r0 = ty * 4, r1 = 64 + ty * 4;

    // Swizzled, thread-constant b128 base offsets (f2v units within a row).
    const int ra0a = swz(r0 >> 1) * 2, ra0b = swz((r0 >> 1) + 1) * 2;
    const int ra1a = swz(r1 >> 1) * 2, ra1b = swz((r1 >> 1) + 1) * 2;
    const int cb0a = swz(c0 >> 1) * 2, cb0b = swz((c0 >> 1) + 1) * 2;
    const int cb1a = swz(c1 >> 1) * 2, cb1b = swz((c1 >> 1) + 1) * 2;

    float acc[2][4][2][4];  // [ri][i][ci][j]
#pragma unroll
    for (int ri = 0; ri < 2; ++ri)
#pragma unroll
        for (int i = 0; i < 4; ++i)
#pragma unroll
            for (int ci = 0; ci < 2; ++ci)
#pragma unroll
                for (int j = 0; j < 4; ++j) acc[ri][i][ci][j] = -INFINITY;

    const float* xb = x + (size_t)(bm + sr) * K_DIM + k0 + 16 * kh;
    const float* wb = W + (size_t)(bn + sr) * K_DIM + k0 + 16 * kh;

    float4 px[4], pw[4];
#pragma unroll
    for (int q = 0; q < 4; ++q) {
        px[q] = *(const float4*)(xb + 4 * q);
        pw[q] = *(const float4*)(wb + 4 * q);
    }

    for (int kt = 0; kt < KT; ++kt) {
        // drain staged registers -> LDS, k-paired, chunk-swizzled
#pragma unroll
        for (int q = 0; q < 4; ++q) {
            const int kp = 8 * kh + 2 * q;
            xs2[kp][srs]     = (f2v){px[q].x, px[q].y};
            xs2[kp + 1][srs] = (f2v){px[q].z, px[q].w};
            ws2[kp][srs]     = (f2v){pw[q].x, pw[q].y};
            ws2[kp + 1][srs] = (f2v){pw[q].z, pw[q].w};
        }
        __syncthreads();

        // prefetch next tile (hidden under compute below); dead when KT==1
        if (kt + 1 < KT) {
            const float* xn = xb + (kt + 1) * BK;
            const float* wn = wb + (kt + 1) * BK;
#pragma unroll
            for (int q = 0; q < 4; ++q) {
                px[q] = *(const float4*)(xn + 4 * q);
                pw[q] = *(const float4*)(wn + 4 * q);
            }
        }

        // 16 k-pairs per tile: 8 b128 reads + 64 x (v_pk_add_f32 + v_max3_f32)
#pragma unroll
        for (int kp = 0; kp < BK / 2; ++kp) {
            f4v A[2][2], B[2][2];
            A[0][0] = *(const f4v*)&xs2[kp][ra0a];
            A[0][1] = *(const f4v*)&xs2[kp][ra0b];
            A[1][0] = *(const f4v*)&xs2[kp][ra1a];
            A[1][1] = *(const f4v*)&xs2[kp][ra1b];
            B[0][0] = *(const f4v*)&ws2[kp][cb0a];
            B[0][1] = *(const f4v*)&ws2[kp][cb0b];
            B[1][0] = *(const f4v*)&ws2[kp][cb1a];
            B[1][1] = *(const f4v*)&ws2[kp][cb1b];

            f2v a2[2][4], b2[2][4];
#pragma unroll
            for (int h = 0; h < 2; ++h) {
                a2[h][0] = A[h][0].xy; a2[h][1] = A[h][0].zw;
                a2[h][2] = A[h][1].xy; a2[h][3] = A[h][1].zw;
                b2[h][0] = B[h][0].xy; b2[h][1] = B[h][0].zw;
                b2[h][2] = B[h][1].xy; b2[h][3] = B[h][1].zw;
            }
#pragma unroll
            for (int ri = 0; ri < 2; ++ri)
#pragma unroll
                for (int i = 0; i < 4; ++i)
#pragma unroll
                    for (int ci = 0; ci < 2; ++ci)
#pragma unroll
                        for (int j = 0; j < 4; ++j) {
                            f2v s = a2[ri][i] + b2[ci][j];      // v_pk_add_f32
                            acc[ri][i][ci][j] =
                                fmaxf(acc[ri][i][ci][j],
                                      fmaxf(s.x, s.y));         // v_max3_f32
                        }
        }
        if (kt + 1 < KT) __syncthreads();   // last tile: no LDS reuse, skip
    }

    // epilogue
    if (USE_WS) {
        float* outp = dst + (size_t)ks * (B_ROWS * O_DIM);
#pragma unroll
        for (int ri = 0; ri < 2; ++ri) {
            const int rb = bm + (ri ? r1 : r0);
#pragma unroll
            for (int i = 0; i < 4; ++i) {
                float4 v0, v1;
                v0.x = acc[ri][i][0][0]; v0.y = acc[ri][i][0][1];
                v0.z = acc[ri][i][0][2]; v0.w = acc[ri][i][0][3];
                v1.x = acc[ri][i][1][0]; v1.y = acc[ri][i][1][1];
                v1.z = acc[ri][i][1][2]; v1.w = acc[ri][i][1][3];
                *(float4*)(outp + (size_t)(rb + i) * O_DIM + bn + c0) = v0;
                *(float4*)(outp + (size_t)(rb + i) * O_DIM + bn + c1) = v1;
            }
        }
    } else {
#pragma unroll
        for (int ri = 0; ri < 2; ++ri) {
            const int rb = bm + (ri ? r1 : r0);
#pragma unroll
            for (int i = 0; i < 4; ++i)
#pragma unroll
                for (int ci = 0; ci < 2; ++ci)
#pragma unroll
                    for (int j = 0; j < 4; ++j) {
                        const int gc = bn + (ci ? c1 : c0) + j;
                        atomic_max_f32(dst + (size_t)(rb + i) * O_DIM + gc,
                                       acc[ri][i][ci][j]);
                    }
        }
    }
}

template <int SPLITK>
__global__ __launch_bounds__(256) void tropical_reduce(
    const float4* __restrict__ ws, float4* __restrict__ out)
{
    const int i = blockIdx.x * 256 + threadIdx.x;   // 0..262143
    const int Q = B_ROWS * O_DIM / 4;               // 262144
    float4 r = ws[i];
#pragma unroll
    for (int p = 1; p < SPLITK; ++p) {
        float4 v = ws[i + p * Q];
        r.x = fmaxf(r.x, v.x);
        r.y = fmaxf(r.y, v.y);
        r.z = fmaxf(r.z, v.z);
        r.w = fmaxf(r.w, v.w);
    }
    out[i] = r;
}

__global__ __launch_bounds__(256) void tropical_fill(float4* __restrict__ out)
{
    const int i = blockIdx.x * 256 + threadIdx.x;
    out[i] = make_float4(-INFINITY, -INFINITY, -INFINITY, -INFINITY);
}

extern "C" void kernel_launch(void* const* d_in, const int* in_sizes, int n_in,
                              void* d_out, int out_size, void* d_ws, size_t ws_size,
                              hipStream_t stream) {
    const float* x = (const float*)d_in[0];   // (2048, 512)
    const float* W = (const float*)d_in[1];   // (512, 512)
    float* out = (float*)d_out;               // (2048, 512)

    const size_t pb16 = 16ull * B_ROWS * O_DIM * sizeof(float);  // 64 MB
    const size_t pb8  = 8ull  * B_ROWS * O_DIM * sizeof(float);  // 32 MB
    const int nred = (B_ROWS * O_DIM / 4) / 256;                 // 1024

    if (ws_size >= pb16) {
        // 1024 blocks -> 4 blocks/CU -> 4 waves/SIMD
        tropical_main<16, 4, true><<<16 * 4 * 16, 256, 0, stream>>>(
            x, W, (float*)d_ws);
        tropical_reduce<16><<<nred, 256, 0, stream>>>(
            (const float4*)d_ws, (float4*)out);
    } else if (ws_size >= pb8) {
        // fallback: proven R3 configuration (+ swizzle)
        tropical_main<8, 2, true><<<16 * 4 * 8, 256, 0, stream>>>(
            x, W, (float*)d_ws);
        tropical_reduce<8><<<nred, 256, 0, stream>>>(
            (const float4*)d_ws, (float4*)out);
    } else {
        tropical_fill<<<nred, 256, 0, stream>>>((float4*)out);
        tropical_main<8, 2, false><<<16 * 4 * 8, 256, 0, stream>>>(x, W, out);
    }
}

// Round 2
// 98.040 us; speedup vs baseline: 1.9306x; 1.9306x over previous
//
#include <hip/hip_runtime.h>
#include <math.h>

// Tropical (max-plus) matmul: out[b,o] = max_k ( x[b,k] + W[o,k] )
// x: (2048,512) f32, W: (512,512) f32, out: (2048,512) f32.
//
// R4 post-mortem: __launch_bounds__(256,4) clamped VGPR to 64 (HW granule)
// -> 64-float acc spilled to scratch -> 550MB HBM traffic, 131us. The
// occupancy theory was never tested.
// R5: SPLITK=16 (1024 blocks -> 4 blocks/CU) with launch_bounds(256,2):
// body compiles to ~112 VGPR (R3-proven), 112 -> 128-granule -> HW still
// co-schedules 4 waves/SIMD; LDS 32KB/block -> 5 blocks/CU. Occupancy
// doubles with no register clamp. Chunk-XOR swizzle kept (refcheck'd).

typedef float f2v __attribute__((ext_vector_type(2)));
typedef float f4v __attribute__((ext_vector_type(4)));

#define B_ROWS 2048
#define K_DIM  512
#define O_DIM  512
#define BM 128
#define BN 128
#define BK 32

// Swizzle 16B chunks (2 f2v) within a 1KB kp-row: c ^= bit3 -> spreads the
// stride-32B read pattern across all 8 bank-groups (4-way -> 2-way = free).
__device__ __forceinline__ int swz(int c) { return c ^ ((c >> 3) & 1); }

__device__ __forceinline__ void atomic_max_f32(float* p, float v) {
    unsigned int* up = (unsigned int*)p;
    unsigned int cur = *(volatile unsigned int*)up;
    while (__uint_as_float(cur) < v) {
        unsigned int assumed = cur;
        cur = atomicCAS(up, assumed, __float_as_uint(v));
        if (cur == assumed) break;
    }
}

template <int SPLITK, bool USE_WS>
__global__ __launch_bounds__(256, 2) void tropical_main(
    const float* __restrict__ x, const float* __restrict__ W,
    float* __restrict__ dst)  // USE_WS: ws partials base; else d_out
{
    constexpr int KRANGE = K_DIM / SPLITK;  // 32 (SK16) / 64 (SK8)
    constexpr int KT     = KRANGE / BK;     // 1 / 2

    // k-pair-major LDS: element [kp][r] = { v[2kp][r], v[2kp+1][r] },
    // with 16B chunks XOR-swizzled within each kp row (both sides).
    __shared__ __align__(16) f2v xs2[BK / 2][BM];   // 16 KB
    __shared__ __align__(16) f2v ws2[BK / 2][BN];   // 16 KB

    const int t  = threadIdx.x;
    const int bx = blockIdx.x;
    const int bn = (bx & 3) * BN;          // 4 N-tiles
    const int bm = ((bx >> 2) & 15) * BM;  // 16 M-tiles
    const int ks = bx >> 6;                // SPLITK K-splits
    const int k0 = ks * KRANGE;

    // Staging: thread t covers 16 consecutive k of one row (4x float4).
    const int sr  = t & 127;          // row within tile
    const int kh  = t >> 7;           // 0/1 -> k-offset 16*kh, kp-offset 8*kh
    const int srs = swz(sr >> 1) * 2 + (sr & 1);   // swizzled f2v slot

    // Compute: 16x16 thread grid, 8x8 register tile as (4+4)x(4+4).
    const int tx = t & 15;
    const int ty = t >> 4;
    const int c0 = tx * 4, c1 = 64 + tx * 4;
    const int r0 = ty * 4, r1 = 64 + ty * 4;

    // Swizzled, thread-constant b128 base offsets (f2v units within a row).
    const int ra0a = swz(r0 >> 1) * 2, ra0b = swz((r0 >> 1) + 1) * 2;
    const int ra1a = swz(r1 >> 1) * 2, ra1b = swz((r1 >> 1) + 1) * 2;
    const int cb0a = swz(c0 >> 1) * 2, cb0b = swz((c0 >> 1) + 1) * 2;
    const int cb1a = swz(c1 >> 1) * 2, cb1b = swz((c1 >> 1) + 1) * 2;

    float acc[2][4][2][4];  // [ri][i][ci][j]
#pragma unroll
    for (int ri = 0; ri < 2; ++ri)
#pragma unroll
        for (int i = 0; i < 4; ++i)
#pragma unroll
            for (int ci = 0; ci < 2; ++ci)
#pragma unroll
                for (int j = 0; j < 4; ++j) acc[ri][i][ci][j] = -INFINITY;

    const float* xb = x + (size_t)(bm + sr) * K_DIM + k0 + 16 * kh;
    const float* wb = W + (size_t)(bn + sr) * K_DIM + k0 + 16 * kh;

    float4 px[4], pw[4];
#pragma unroll
    for (int q = 0; q < 4; ++q) {
        px[q] = *(const float4*)(xb + 4 * q);
        pw[q] = *(const float4*)(wb + 4 * q);
    }

    for (int kt = 0; kt < KT; ++kt) {
        // drain staged registers -> LDS, k-paired, chunk-swizzled
#pragma unroll
        for (int q = 0; q < 4; ++q) {
            const int kp = 8 * kh + 2 * q;
            xs2[kp][srs]     = (f2v){px[q].x, px[q].y};
            xs2[kp + 1][srs] = (f2v){px[q].z, px[q].w};
            ws2[kp][srs]     = (f2v){pw[q].x, pw[q].y};
            ws2[kp + 1][srs] = (f2v){pw[q].z, pw[q].w};
        }
        __syncthreads();

        // prefetch next tile (hidden under compute below); dead when KT==1
        if (kt + 1 < KT) {
            const float* xn = xb + (kt + 1) * BK;
            const float* wn = wb + (kt + 1) * BK;
#pragma unroll
            for (int q = 0; q < 4; ++q) {
                px[q] = *(const float4*)(xn + 4 * q);
                pw[q] = *(const float4*)(wn + 4 * q);
            }
        }

        // 16 k-pairs per tile: 8 b128 reads + 64 x (v_pk_add_f32 + v_max3_f32)
#pragma unroll
        for (int kp = 0; kp < BK / 2; ++kp) {
            f4v A[2][2], B[2][2];
            A[0][0] = *(const f4v*)&xs2[kp][ra0a];
            A[0][1] = *(const f4v*)&xs2[kp][ra0b];
            A[1][0] = *(const f4v*)&xs2[kp][ra1a];
            A[1][1] = *(const f4v*)&xs2[kp][ra1b];
            B[0][0] = *(const f4v*)&ws2[kp][cb0a];
            B[0][1] = *(const f4v*)&ws2[kp][cb0b];
            B[1][0] = *(const f4v*)&ws2[kp][cb1a];
            B[1][1] = *(const f4v*)&ws2[kp][cb1b];

            f2v a2[2][4], b2[2][4];
#pragma unroll
            for (int h = 0; h < 2; ++h) {
                a2[h][0] = A[h][0].xy; a2[h][1] = A[h][0].zw;
                a2[h][2] = A[h][1].xy; a2[h][3] = A[h][1].zw;
                b2[h][0] = B[h][0].xy; b2[h][1] = B[h][0].zw;
                b2[h][2] = B[h][1].xy; b2[h][3] = B[h][1].zw;
            }
#pragma unroll
            for (int ri = 0; ri < 2; ++ri)
#pragma unroll
                for (int i = 0; i < 4; ++i)
#pragma unroll
                    for (int ci = 0; ci < 2; ++ci)
#pragma unroll
                        for (int j = 0; j < 4; ++j) {
                            f2v s = a2[ri][i] + b2[ci][j];      // v_pk_add_f32
                            acc[ri][i][ci][j] =
                                fmaxf(acc[ri][i][ci][j],
                                      fmaxf(s.x, s.y));         // v_max3_f32
                        }
        }
        if (kt + 1 < KT) __syncthreads();   // last tile: no LDS reuse, skip
    }

    // epilogue
    if (USE_WS) {
        float* outp = dst + (size_t)ks * (B_ROWS * O_DIM);
#pragma unroll
        for (int ri = 0; ri < 2; ++ri) {
            const int rb = bm + (ri ? r1 : r0);
#pragma unroll
            for (int i = 0; i < 4; ++i) {
                float4 v0, v1;
                v0.x = acc[ri][i][0][0]; v0.y = acc[ri][i][0][1];
                v0.z = acc[ri][i][0][2]; v0.w = acc[ri][i][0][3];
                v1.x = acc[ri][i][1][0]; v1.y = acc[ri][i][1][1];
                v1.z = acc[ri][i][1][2]; v1.w = acc[ri][i][1][3];
                *(float4*)(outp + (size_t)(rb + i) * O_DIM + bn + c0) = v0;
                *(float4*)(outp + (size_t)(rb + i) * O_DIM + bn + c1) = v1;
            }
        }
    } else {
#pragma unroll
        for (int ri = 0; ri < 2; ++ri) {
            const int rb = bm + (ri ? r1 : r0);
#pragma unroll
            for (int i = 0; i < 4; ++i)
#pragma unroll
                for (int ci = 0; ci < 2; ++ci)
#pragma unroll
                    for (int j = 0; j < 4; ++j) {
                        const int gc = bn + (ci ? c1 : c0) + j;
                        atomic_max_f32(dst + (size_t)(rb + i) * O_DIM + gc,
                                       acc[ri][i][ci][j]);
                    }
        }
    }
}

template <int SPLITK>
__global__ __launch_bounds__(256) void tropical_reduce(
    const float4* __restrict__ ws, float4* __restrict__ out)
{
    const int i = blockIdx.x * 256 + threadIdx.x;   // 0..262143
    const int Q = B_ROWS * O_DIM / 4;               // 262144
    float4 r = ws[i];
#pragma unroll
    for (int p = 1; p < SPLITK; ++p) {
        float4 v = ws[i + p * Q];
        r.x = fmaxf(r.x, v.x);
        r.y = fmaxf(r.y, v.y);
        r.z = fmaxf(r.z, v.z);
        r.w = fmaxf(r.w, v.w);
    }
    out[i] = r;
}

__global__ __launch_bounds__(256) void tropical_fill(float4* __restrict__ out)
{
    const int i = blockIdx.x * 256 + threadIdx.x;
    out[i] = make_float4(-INFINITY, -INFINITY, -INFINITY, -INFINITY);
}

extern "C" void kernel_launch(void* const* d_in, const int* in_sizes, int n_in,
                              void* d_out, int out_size, void* d_ws, size_t ws_size,
                              hipStream_t stream) {
    const float* x = (const float*)d_in[0];   // (2048, 512)
    const float* W = (const float*)d_in[1];   // (512, 512)
    float* out = (float*)d_out;               // (2048, 512)

    const size_t pb16 = 16ull * B_ROWS * O_DIM * sizeof(float);  // 64 MB
    const size_t pb8  = 8ull  * B_ROWS * O_DIM * sizeof(float);  // 32 MB
    const int nred = (B_ROWS * O_DIM / 4) / 256;                 // 1024

    if (ws_size >= pb16) {
        // 1024 blocks -> 4 blocks/CU -> 4 waves/SIMD (no VGPR clamp)
        tropical_main<16, true><<<16 * 4 * 16, 256, 0, stream>>>(
            x, W, (float*)d_ws);
        tropical_reduce<16><<<nred, 256, 0, stream>>>(
            (const float4*)d_ws, (float4*)out);
    } else if (ws_size >= pb8) {
        // fallback: proven R3 configuration (+ swizzle)
        tropical_main<8, true><<<16 * 4 * 8, 256, 0, stream>>>(
            x, W, (float*)d_ws);
        tropical_reduce<8><<<nred, 256, 0, stream>>>(
            (const float4*)d_ws, (float4*)out);
    } else {
        tropical_fill<<<nred, 256, 0, stream>>>((float4*)out);
        tropical_main<8, false><<<16 * 4 * 8, 256, 0, stream>>>(x, W, out);
    }
}

// Round 3
// 93.432 us; speedup vs baseline: 2.0258x; 1.0493x over previous
//
#include <hip/hip_runtime.h>
#include <math.h>

// Tropical (max-plus) matmul: out[b,o] = max_k ( x[b,k] + W[o,k] )
// x: (2048,512) f32, W: (512,512) f32, out: (2048,512) f32.
//
// R5 post-mortem: SK16 doubled grid (2->4 blocks/CU available) and NOTHING
// moved (dur, VALUBusy 25%, occupancy 18.5% all flat) -> not grid/occupancy
// limited. Bank conflicts ruled out (constant 2^20 = benign staging-write
// cycles in every variant). Remaining suspect matching all evidence
// (occupancy-insensitive, splitk-insensitive, 75% stall): the fully
// unrolled 16-kp body is ~40-50KB of straight-line code > 32KB L1I; waves
// at different PCs thrash I$ continuously.
// R6: #pragma unroll 4 on the kp loop (~13KB body, I$-resident); revert to
// SPLITK=8 (SK16 only doubled reduce traffic). Everything else unchanged.

typedef float f2v __attribute__((ext_vector_type(2)));
typedef float f4v __attribute__((ext_vector_type(4)));

#define B_ROWS 2048
#define K_DIM  512
#define O_DIM  512
#define BM 128
#define BN 128
#define BK 32
#define SPLITK 8
#define KRANGE (K_DIM / SPLITK)   // 64
#define KT     (KRANGE / BK)      // 2 tiles per block

// Swizzle 16B chunks (2 f2v) within a 1KB kp-row (verified-correct; perf
// neutral but kept to avoid churn).
__device__ __forceinline__ int swz(int c) { return c ^ ((c >> 3) & 1); }

__device__ __forceinline__ void atomic_max_f32(float* p, float v) {
    unsigned int* up = (unsigned int*)p;
    unsigned int cur = *(volatile unsigned int*)up;
    while (__uint_as_float(cur) < v) {
        unsigned int assumed = cur;
        cur = atomicCAS(up, assumed, __float_as_uint(v));
        if (cur == assumed) break;
    }
}

template <bool USE_WS>
__global__ __launch_bounds__(256, 2) void tropical_main(
    const float* __restrict__ x, const float* __restrict__ W,
    float* __restrict__ dst)  // USE_WS: ws partials base; else d_out
{
    // k-pair-major LDS: element [kp][r] = { v[2kp][r], v[2kp+1][r] }.
    __shared__ __align__(16) f2v xs2[BK / 2][BM];   // 16 KB
    __shared__ __align__(16) f2v ws2[BK / 2][BN];   // 16 KB

    const int t  = threadIdx.x;
    const int bx = blockIdx.x;
    const int bn = (bx & 3) * BN;          // 4 N-tiles
    const int bm = ((bx >> 2) & 15) * BM;  // 16 M-tiles
    const int ks = bx >> 6;                // 8 K-splits
    const int k0 = ks * KRANGE;

    // Staging: thread t covers 16 consecutive k of one row (4x float4).
    const int sr  = t & 127;          // row within tile
    const int kh  = t >> 7;           // 0/1 -> k-offset 16*kh, kp-offset 8*kh
    const int srs = swz(sr >> 1) * 2 + (sr & 1);   // swizzled f2v slot

    // Compute: 16x16 thread grid, 8x8 register tile as (4+4)x(4+4).
    const int tx = t & 15;
    const int ty = t >> 4;
    const int c0 = tx * 4, c1 = 64 + tx * 4;
    const int r0 = ty * 4, r1 = 64 + ty * 4;

    // Swizzled, thread-constant b128 base offsets (f2v units within a row).
    const int ra0a = swz(r0 >> 1) * 2, ra0b = swz((r0 >> 1) + 1) * 2;
    const int ra1a = swz(r1 >> 1) * 2, ra1b = swz((r1 >> 1) + 1) * 2;
    const int cb0a = swz(c0 >> 1) * 2, cb0b = swz((c0 >> 1) + 1) * 2;
    const int cb1a = swz(c1 >> 1) * 2, cb1b = swz((c1 >> 1) + 1) * 2;

    float acc[2][4][2][4];  // [ri][i][ci][j]
#pragma unroll
    for (int ri = 0; ri < 2; ++ri)
#pragma unroll
        for (int i = 0; i < 4; ++i)
#pragma unroll
            for (int ci = 0; ci < 2; ++ci)
#pragma unroll
                for (int j = 0; j < 4; ++j) acc[ri][i][ci][j] = -INFINITY;

    const float* xb = x + (size_t)(bm + sr) * K_DIM + k0 + 16 * kh;
    const float* wb = W + (size_t)(bn + sr) * K_DIM + k0 + 16 * kh;

    float4 px[4], pw[4];
#pragma unroll
    for (int q = 0; q < 4; ++q) {
        px[q] = *(const float4*)(xb + 4 * q);
        pw[q] = *(const float4*)(wb + 4 * q);
    }

    for (int kt = 0; kt < KT; ++kt) {
        // drain staged registers -> LDS, k-paired, chunk-swizzled
#pragma unroll
        for (int q = 0; q < 4; ++q) {
            const int kp = 8 * kh + 2 * q;
            xs2[kp][srs]     = (f2v){px[q].x, px[q].y};
            xs2[kp + 1][srs] = (f2v){px[q].z, px[q].w};
            ws2[kp][srs]     = (f2v){pw[q].x, pw[q].y};
            ws2[kp + 1][srs] = (f2v){pw[q].z, pw[q].w};
        }
        __syncthreads();

        // prefetch next tile (hidden under compute below)
        if (kt + 1 < KT) {
            const float* xn = xb + (kt + 1) * BK;
            const float* wn = wb + (kt + 1) * BK;
#pragma unroll
            for (int q = 0; q < 4; ++q) {
                px[q] = *(const float4*)(xn + 4 * q);
                pw[q] = *(const float4*)(wn + 4 * q);
            }
        }

        // 16 k-pairs: partial unroll x4 so the loop body (~13KB) stays
        // L1I-resident; full 16x unroll was ~50KB of straight-line code.
#pragma unroll 4
        for (int kp = 0; kp < BK / 2; ++kp) {
            f4v A[2][2], B[2][2];
            A[0][0] = *(const f4v*)&xs2[kp][ra0a];
            A[0][1] = *(const f4v*)&xs2[kp][ra0b];
            A[1][0] = *(const f4v*)&xs2[kp][ra1a];
            A[1][1] = *(const f4v*)&xs2[kp][ra1b];
            B[0][0] = *(const f4v*)&ws2[kp][cb0a];
            B[0][1] = *(const f4v*)&ws2[kp][cb0b];
            B[1][0] = *(const f4v*)&ws2[kp][cb1a];
            B[1][1] = *(const f4v*)&ws2[kp][cb1b];

            f2v a2[2][4], b2[2][4];
#pragma unroll
            for (int h = 0; h < 2; ++h) {
                a2[h][0] = A[h][0].xy; a2[h][1] = A[h][0].zw;
                a2[h][2] = A[h][1].xy; a2[h][3] = A[h][1].zw;
                b2[h][0] = B[h][0].xy; b2[h][1] = B[h][0].zw;
                b2[h][2] = B[h][1].xy; b2[h][3] = B[h][1].zw;
            }
#pragma unroll
            for (int ri = 0; ri < 2; ++ri)
#pragma unroll
                for (int i = 0; i < 4; ++i)
#pragma unroll
                    for (int ci = 0; ci < 2; ++ci)
#pragma unroll
                        for (int j = 0; j < 4; ++j) {
                            f2v s = a2[ri][i] + b2[ci][j];      // v_pk_add_f32
                            acc[ri][i][ci][j] =
                                fmaxf(acc[ri][i][ci][j],
                                      fmaxf(s.x, s.y));         // v_max3_f32
                        }
        }
        if (kt + 1 < KT) __syncthreads();   // last tile: no LDS reuse, skip
    }

    // epilogue
    if (USE_WS) {
        float* outp = dst + (size_t)ks * (B_ROWS * O_DIM);
#pragma unroll
        for (int ri = 0; ri < 2; ++ri) {
            const int rb = bm + (ri ? r1 : r0);
#pragma unroll
            for (int i = 0; i < 4; ++i) {
                float4 v0, v1;
                v0.x = acc[ri][i][0][0]; v0.y = acc[ri][i][0][1];
                v0.z = acc[ri][i][0][2]; v0.w = acc[ri][i][0][3];
                v1.x = acc[ri][i][1][0]; v1.y = acc[ri][i][1][1];
                v1.z = acc[ri][i][1][2]; v1.w = acc[ri][i][1][3];
                *(float4*)(outp + (size_t)(rb + i) * O_DIM + bn + c0) = v0;
                *(float4*)(outp + (size_t)(rb + i) * O_DIM + bn + c1) = v1;
            }
        }
    } else {
#pragma unroll
        for (int ri = 0; ri < 2; ++ri) {
            const int rb = bm + (ri ? r1 : r0);
#pragma unroll
            for (int i = 0; i < 4; ++i)
#pragma unroll
                for (int ci = 0; ci < 2; ++ci)
#pragma unroll
                    for (int j = 0; j < 4; ++j) {
                        const int gc = bn + (ci ? c1 : c0) + j;
                        atomic_max_f32(dst + (size_t)(rb + i) * O_DIM + gc,
                                       acc[ri][i][ci][j]);
                    }
        }
    }
}

__global__ __launch_bounds__(256) void tropical_reduce(
    const float4* __restrict__ ws, float4* __restrict__ out)
{
    const int i = blockIdx.x * 256 + threadIdx.x;   // 0..262143
    const int Q = B_ROWS * O_DIM / 4;               // 262144
    float4 r = ws[i];
#pragma unroll
    for (int p = 1; p < SPLITK; ++p) {
        float4 v = ws[i + p * Q];
        r.x = fmaxf(r.x, v.x);
        r.y = fmaxf(r.y, v.y);
        r.z = fmaxf(r.z, v.z);
        r.w = fmaxf(r.w, v.w);
    }
    out[i] = r;
}

__global__ __launch_bounds__(256) void tropical_fill(float4* __restrict__ out)
{
    const int i = blockIdx.x * 256 + threadIdx.x;
    out[i] = make_float4(-INFINITY, -INFINITY, -INFINITY, -INFINITY);
}

extern "C" void kernel_launch(void* const* d_in, const int* in_sizes, int n_in,
                              void* d_out, int out_size, void* d_ws, size_t ws_size,
                              hipStream_t stream) {
    const float* x = (const float*)d_in[0];   // (2048, 512)
    const float* W = (const float*)d_in[1];   // (512, 512)
    float* out = (float*)d_out;               // (2048, 512)

    const size_t partial_bytes = (size_t)SPLITK * B_ROWS * O_DIM * sizeof(float);
    const int nblocks = 16 * 4 * SPLITK;      // 512
    const int nred = (B_ROWS * O_DIM / 4) / 256;   // 1024

    if (ws_size >= partial_bytes) {
        tropical_main<true><<<nblocks, 256, 0, stream>>>(x, W, (float*)d_ws);
        tropical_reduce<<<nred, 256, 0, stream>>>(
            (const float4*)d_ws, (float4*)out);
    } else {
        tropical_fill<<<nred, 256, 0, stream>>>((float4*)out);
        tropical_main<false><<<nblocks, 256, 0, stream>>>(x, W, out);
    }
}